// Round 1
// baseline (29482.925 us; speedup 1.0000x reference)
//
#include <hip/hip_runtime.h>
#include <cstdint>

// LSTM persistent kernel for MI355X (gfx950).
// B=256, T=1024, I=128, H=256, O=128. All inputs/outputs fp32.
//
// Grid: 256 workgroups = 16 batch-groups (16 rows each) x 16 column-tiles
// (16 h-cols each -> 64 gate cols). One WG per CU (forced by 138 KB LDS).
// Weights live in registers as bf16 hi/lo MFMA B-fragments (bf16x3 split
// products give ~2^-17 relative accuracy; c-state stays fp32 in VGPRs).
// Per-step h exchange between the 16 column-peers of a batch group goes
// through L3 with agent-scope fences + step-tagged flags (0xAA-poison safe).

#define T_    1024
#define I_    128
#define H_    256

typedef short s8v __attribute__((ext_vector_type(8)));
typedef float f4v __attribute__((ext_vector_type(4)));
typedef unsigned short u16;
typedef unsigned int   u32;

__device__ __forceinline__ u16 f2bf(float f) {
  union { float f; u32 u; } v; v.f = f;
  u32 r = v.u + 0x7FFFu + ((v.u >> 16) & 1u);
  return (u16)(r >> 16);
}
__device__ __forceinline__ float bf2f(u16 h) {
  union { u32 u; float f; } v; v.u = ((u32)h) << 16;
  return v.f;
}
__device__ __forceinline__ float sig_(float x)  { return 1.0f / (1.0f + __expf(-x)); }
__device__ __forceinline__ float tanh_(float x) { return 2.0f / (1.0f + __expf(-2.0f * x)) - 1.0f; }

__global__ __launch_bounds__(256, 1) void lstm_persist(
    const float* __restrict__ x, const float* __restrict__ Wih,
    const float* __restrict__ Whh, const float* __restrict__ bih,
    const float* __restrict__ bhh, const float* __restrict__ Wout,
    const float* __restrict__ bout, float* __restrict__ out,
    u32* __restrict__ flags, u16* __restrict__ hbuf)
{
  const int bid  = blockIdx.x;
  // XCD co-location heuristic: members (column tiles) of one batch group get
  // blockIdx with equal (bid % 8) so they land on one XCD (perf-only).
  const int xcd  = bid & 7;
  const int slot = bid >> 3;
  const int ct   = slot & 15;                 // column tile (0..15)
  const int g    = ((slot >> 4) << 3) | xcd;  // batch group (0..15)
  const int tid  = threadIdx.x;
  const int wave = tid >> 6;
  const int lane = tid & 63;
  const int lm   = lane & 15;   // MFMA m (A) / n (B) index
  const int lq   = lane >> 4;   // MFMA quad

  __shared__ u16   Wlds[2][64][392];        // setup W staging; reused for W_out
  __shared__ u16   xlds[2][2][16][136];     // [parity][hi/lo][m][k(128)+pad]
  __shared__ float partial[4][4][16][20];   // [wave][gate][m][hc+pad]

  // ---- stage W slice (concat Wih rows 0..127, Whh rows 128..383) col-major ----
  for (int it = tid; it < 384 * 64; it += 256) {
    int k = it >> 6;
    int c = it & 63;                              // gate = c>>4, n = c&15
    int gcol = (c >> 4) * 256 + ct * 16 + (c & 15);
    float w = (k < 128) ? Wih[k * 1024 + gcol] : Whh[(k - 128) * 1024 + gcol];
    u16 hi = f2bf(w);
    Wlds[0][c][k] = hi;
    Wlds[1][c][k] = f2bf(w - bf2f(hi));
  }
  __syncthreads();

  // ---- per-wave W fragments in registers: wave owns k-tiles {w, w+4, w+8} ----
  // B-frag layout (16x16x32): lane holds B[k = lq*8+j][n = lm], j=0..7.
  s8v wfrag[3][4][2];
  #pragma unroll
  for (int ki = 0; ki < 3; ki++) {
    const int kt = wave + 4 * ki;
    #pragma unroll
    for (int gg = 0; gg < 4; gg++) {
      #pragma unroll
      for (int p = 0; p < 2; p++)
        wfrag[ki][gg][p] = *(const s8v*)&Wlds[p][gg * 16 + lm][kt * 32 + lq * 8];
    }
  }
  __syncthreads();

  // cell-update thread mapping: one thread per (batch m, h-col)
  const int cm  = tid >> 4;
  const int chc = tid & 15;
  float biasv[4];
  #pragma unroll
  for (int gg = 0; gg < 4; gg++) {
    int col = gg * 256 + ct * 16 + chc;
    biasv[gg] = bih[col] + bhh[col];
  }
  float cstate = 0.0f;

  // x prefetch mapping: thread loads x[g*16+xr][t][xc0..xc0+7]
  const int xr  = tid >> 4;
  const int xc0 = (tid & 15) * 8;
  const float* xbase = x + (size_t)(g * 16 + xr) * (T_ * I_) + xc0;

  u32* gflags = flags + g * 32;                      // 128 B per group
  const size_t hpar   = (size_t)16 * 2 * 16 * 256;   // parity stride (u16 elems)
  const size_t hgbase = (size_t)g * 2 * 16 * 256;    // group base within parity

  auto xstore = [&](int par, float4 a, float4 b) {
    float v[8] = {a.x, a.y, a.z, a.w, b.x, b.y, b.z, b.w};
    union { u16 u[8]; s8v s; } hi, lo;
    #pragma unroll
    for (int j = 0; j < 8; j++) {
      u16 h = f2bf(v[j]);
      hi.u[j] = h;
      lo.u[j] = f2bf(v[j] - bf2f(h));
    }
    *(s8v*)&xlds[par][0][xr][xc0] = hi.s;
    *(s8v*)&xlds[par][1][xr][xc0] = lo.s;
  };

  { // x_0 into parity 0
    float4 a = *(const float4*)(xbase + 0);
    float4 b = *(const float4*)(xbase + 4);
    xstore(0, a, b);
  }
  __syncthreads();

  for (int t = 0; t < T_; t++) {
    const int par = t & 1;
    const int pn  = (t + 1) & 1;

    // prefetch x_{t+1} (clamped; read-only data, safe before fences)
    const int tn = (t + 1 < T_) ? (t + 1) : t;
    float4 xa = *(const float4*)(xbase + (size_t)tn * I_);
    float4 xb = *(const float4*)(xbase + (size_t)tn * I_ + 4);

    f4v acc[4];
    #pragma unroll
    for (int gg = 0; gg < 4; gg++)
      #pragma unroll
      for (int r = 0; r < 4; r++) acc[gg][r] = 0.0f;

    // x-part MFMA (k-tile = wave), independent of peers -> runs before spin.
    // A-frag layout: lane holds A[m = lm][k = lq*8+j].
    {
      s8v axh = *(const s8v*)&xlds[par][0][lm][wave * 32 + lq * 8];
      s8v axl = *(const s8v*)&xlds[par][1][lm][wave * 32 + lq * 8];
      #pragma unroll
      for (int gg = 0; gg < 4; gg++) {
        acc[gg] = __builtin_amdgcn_mfma_f32_16x16x32_bf16(axh, wfrag[0][gg][0], acc[gg], 0, 0, 0);
        acc[gg] = __builtin_amdgcn_mfma_f32_16x16x32_bf16(axl, wfrag[0][gg][0], acc[gg], 0, 0, 0);
        acc[gg] = __builtin_amdgcn_mfma_f32_16x16x32_bf16(axh, wfrag[0][gg][1], acc[gg], 0, 0, 0);
      }
    }

    if (t > 0) {
      // spin until all 16 peers posted h_t (flag==t; skew can make it t+1).
      // 0xAAAAAAAA poison never satisfies (f - t) <= 1.
      const u32 s = (u32)t;
      u32* fp = gflags + lm;
      while (true) {
        u32 f = __hip_atomic_load(fp, __ATOMIC_RELAXED, __HIP_MEMORY_SCOPE_AGENT);
        if (__all((int)((f - s) <= 1u))) break;
        __builtin_amdgcn_s_sleep(1);
      }
      __builtin_amdgcn_fence(__ATOMIC_ACQUIRE, "agent");

      const u16* hb0 = hbuf + (size_t)par * hpar + hgbase;
      #pragma unroll
      for (int ki = 1; ki < 3; ki++) {
        const int kt = wave + 4 * ki;
        const int hk = kt * 32 - 128 + lq * 8;   // k within h (0..255)
        s8v ahh = *(const s8v*)&hb0[(size_t)lm * 256 + hk];          // hi plane
        s8v ahl = *(const s8v*)&hb0[(size_t)(16 + lm) * 256 + hk];   // lo plane
        #pragma unroll
        for (int gg = 0; gg < 4; gg++) {
          acc[gg] = __builtin_amdgcn_mfma_f32_16x16x32_bf16(ahh, wfrag[ki][gg][0], acc[gg], 0, 0, 0);
          acc[gg] = __builtin_amdgcn_mfma_f32_16x16x32_bf16(ahl, wfrag[ki][gg][0], acc[gg], 0, 0, 0);
          acc[gg] = __builtin_amdgcn_mfma_f32_16x16x32_bf16(ahh, wfrag[ki][gg][1], acc[gg], 0, 0, 0);
        }
      }
    }

    // write per-wave partial gates (C layout: col=lm, row=lq*4+r)
    #pragma unroll
    for (int gg = 0; gg < 4; gg++)
      #pragma unroll
      for (int r = 0; r < 4; r++)
        partial[wave][gg][lq * 4 + r][lm] = acc[gg][r];
    __syncthreads();

    // cell update: thread (cm, chc)
    float ga = biasv[0], gb = biasv[1], gc = biasv[2], gd = biasv[3];
    #pragma unroll
    for (int w = 0; w < 4; w++) {
      ga += partial[w][0][cm][chc];
      gb += partial[w][1][cm][chc];
      gc += partial[w][2][cm][chc];
      gd += partial[w][3][cm][chc];
    }
    float i_t = sig_(ga), f_t = sig_(gb), g_t = tanh_(gc), o_t = sig_(gd);
    cstate = f_t * cstate + i_t * g_t;
    float h = o_t * tanh_(cstate);

    // publish h_{t+1} as hi/lo bf16 planes
    u16 hhi = f2bf(h);
    u16 hlo = f2bf(h - bf2f(hhi));
    u16* hw = hbuf + (size_t)pn * hpar + hgbase;
    hw[(size_t)cm * 256 + ct * 16 + chc]        = hhi;
    hw[(size_t)(16 + cm) * 256 + ct * 16 + chc] = hlo;
    __builtin_amdgcn_fence(__ATOMIC_RELEASE, "agent");
    __syncthreads();
    if (tid == 0)
      __hip_atomic_store(gflags + ct, (u32)(t + 1), __ATOMIC_RELEASE, __HIP_MEMORY_SCOPE_AGENT);

    // convert x_{t+1} into the other parity's LDS planes
    xstore(pn, xa, xb);
    __syncthreads();
  }

  // ---- output projection: out = h_T @ W_out + b_out ----
  {
    const u32 s = (u32)T_;
    u32* fp = gflags + lm;
    while (true) {
      u32 f = __hip_atomic_load(fp, __ATOMIC_RELAXED, __HIP_MEMORY_SCOPE_AGENT);
      if (__all((int)((f - s) <= 1u))) break;
      __builtin_amdgcn_s_sleep(1);
    }
    __builtin_amdgcn_fence(__ATOMIC_ACQUIRE, "agent");
  }
  __syncthreads();
  // stage W_out cols [ct*8, ct*8+8) into Wlds[p][n][k], zero-pad n in [8,16)
  for (int it = tid; it < 16 * 256; it += 256) {
    int n = it >> 8;
    int k = it & 255;
    float w = (n < 8) ? Wout[k * 128 + ct * 8 + n] : 0.0f;
    u16 hi = f2bf(w);
    Wlds[0][n][k] = hi;
    Wlds[1][n][k] = f2bf(w - bf2f(hi));
  }
  __syncthreads();

  f4v oacc;
  #pragma unroll
  for (int r = 0; r < 4; r++) oacc[r] = 0.0f;
  const u16* hb0 = hbuf + hgbase;   // h_T lives at parity (1024 & 1) == 0
  #pragma unroll
  for (int ki = 0; ki < 2; ki++) {
    const int hk = (wave * 2 + ki) * 32 + lq * 8;
    s8v ahh = *(const s8v*)&hb0[(size_t)lm * 256 + hk];
    s8v ahl = *(const s8v*)&hb0[(size_t)(16 + lm) * 256 + hk];
    s8v bh  = *(const s8v*)&Wlds[0][lm][hk];
    s8v bl  = *(const s8v*)&Wlds[1][lm][hk];
    oacc = __builtin_amdgcn_mfma_f32_16x16x32_bf16(ahh, bh, oacc, 0, 0, 0);
    oacc = __builtin_amdgcn_mfma_f32_16x16x32_bf16(ahl, bh, oacc, 0, 0, 0);
    oacc = __builtin_amdgcn_mfma_f32_16x16x32_bf16(ahh, bl, oacc, 0, 0, 0);
  }
  #pragma unroll
  for (int r = 0; r < 4; r++) partial[wave][0][lq * 4 + r][lm] = oacc[r];
  __syncthreads();

  if (tid < 128) {
    int m  = tid >> 3;
    int oc = tid & 7;
    float v = bout[ct * 8 + oc];
    #pragma unroll
    for (int w = 0; w < 4; w++) v += partial[w][0][m][oc];
    out[(size_t)(g * 16 + m) * 128 + ct * 8 + oc] = v;
  }
}

extern "C" void kernel_launch(void* const* d_in, const int* in_sizes, int n_in,
                              void* d_out, int out_size, void* d_ws, size_t ws_size,
                              hipStream_t stream) {
  const float* x    = (const float*)d_in[0];
  const float* Wih  = (const float*)d_in[1];
  const float* Whh  = (const float*)d_in[2];
  const float* bih  = (const float*)d_in[3];
  const float* bhh  = (const float*)d_in[4];
  const float* Wout = (const float*)d_in[5];
  const float* bout = (const float*)d_in[6];
  float* out = (float*)d_out;

  char* ws = (char*)d_ws;
  u32* flags = (u32*)ws;               // 16 groups * 128 B = 2 KB (poison-safe protocol)
  u16* hbuf  = (u16*)(ws + 4096);      // 2 parities * 16 groups * 2 planes * 16 * 256 * 2 B = 512 KB

  hipLaunchKernelGGL(lstm_persist, dim3(256), dim3(256), 0, stream,
                     x, Wih, Whh, bih, bhh, Wout, bout, out, flags, hbuf);
}

// Round 2
// 3151.108 us; speedup vs baseline: 9.3564x; 9.3564x over previous
//
#include <hip/hip_runtime.h>
#include <cstdint>

// LSTM persistent kernel for MI355X (gfx950), round 2.
// B=256, T=1024, I=128, H=256, O=128. All inputs/outputs fp32.
//
// Grid: 256 WGs = 16 batch-groups x 16 column-tiles; one WG/CU (forced by LDS).
// Weights in registers as bf16 hi/lo MFMA B-fragments (bf16x3 split products).
// R2 change: per-step h exchange uses RELAXED agent-scope atomics (sc1
// write-through loads/stores, coherent at L3) instead of agent fences.
// fence(acquire/release, agent) lowers to buffer_inv/buffer_wbl2 (full per-XCD
// L2 maintenance) -> that was ~28 us/step in R1. Ordering now comes from the
// s_waitcnt vmcnt(0) that __syncthreads emits (h stores drained before the
// flag store) + control dependence of the coherent h loads on the flag value.

#define T_    1024
#define I_    128
#define H_    256

typedef short s8v __attribute__((ext_vector_type(8)));
typedef float f4v __attribute__((ext_vector_type(4)));
typedef unsigned short u16;
typedef unsigned int   u32;
typedef unsigned long long u64;

__device__ __forceinline__ u16 f2bf(float f) {
  union { float f; u32 u; } v; v.f = f;
  u32 r = v.u + 0x7FFFu + ((v.u >> 16) & 1u);
  return (u16)(r >> 16);
}
__device__ __forceinline__ float bf2f(u16 h) {
  union { u32 u; float f; } v; v.u = ((u32)h) << 16;
  return v.f;
}
__device__ __forceinline__ float sig_(float x)  { return 1.0f / (1.0f + __expf(-x)); }
__device__ __forceinline__ float tanh_(float x) { return 2.0f / (1.0f + __expf(-2.0f * x)) - 1.0f; }

// unpack 4x u64 (8 packed elements: lo16=hi-bf16, hi16=lo-bf16) -> hi/lo s8v
__device__ __forceinline__ void unpack8(const u64 w[4], s8v& hi, s8v& lo) {
  #pragma unroll
  for (int j = 0; j < 4; j++) {
    u32 a = (u32)w[j], b = (u32)(w[j] >> 32);
    hi[2*j]   = (short)(u16)a;        lo[2*j]   = (short)(u16)(a >> 16);
    hi[2*j+1] = (short)(u16)b;        lo[2*j+1] = (short)(u16)(b >> 16);
  }
}

__global__ __launch_bounds__(256, 1) void lstm_persist(
    const float* __restrict__ x, const float* __restrict__ Wih,
    const float* __restrict__ Whh, const float* __restrict__ bih,
    const float* __restrict__ bhh, const float* __restrict__ Wout,
    const float* __restrict__ bout, float* __restrict__ out,
    u32* __restrict__ flags, u32* __restrict__ hbuf)
{
  const int bid  = blockIdx.x;
  // XCD co-location heuristic (perf-only): group members share bid&7.
  const int xcd  = bid & 7;
  const int slot = bid >> 3;
  const int ct   = slot & 15;                 // column tile (0..15)
  const int g    = ((slot >> 4) << 3) | xcd;  // batch group (0..15)
  const int tid  = threadIdx.x;
  const int wave = tid >> 6;
  const int lane = tid & 63;
  const int lm   = lane & 15;   // MFMA m (A) / n (B) index
  const int lq   = lane >> 4;   // MFMA quad

  __shared__ u16   Wlds[2][64][392];        // setup W staging; reused for W_out
  __shared__ u16   xlds[2][2][16][136];     // [parity][hi/lo][m][k(128)+pad]
  __shared__ float partial[4][4][16][20];   // [wave][gate][m][hc+pad]

  // ---- stage W slice (concat Wih rows 0..127, Whh rows 128..383) col-major ----
  for (int it = tid; it < 384 * 64; it += 256) {
    int k = it >> 6;
    int c = it & 63;                              // gate = c>>4, n = c&15
    int gcol = (c >> 4) * 256 + ct * 16 + (c & 15);
    float w = (k < 128) ? Wih[k * 1024 + gcol] : Whh[(k - 128) * 1024 + gcol];
    u16 hi = f2bf(w);
    Wlds[0][c][k] = hi;
    Wlds[1][c][k] = f2bf(w - bf2f(hi));
  }
  __syncthreads();

  // ---- per-wave W fragments in registers: wave owns k-tiles {w, w+4, w+8} ----
  // B-frag layout (16x16x32): lane holds B[k = lq*8+j][n = lm], j=0..7.
  s8v wfrag[3][4][2];
  #pragma unroll
  for (int ki = 0; ki < 3; ki++) {
    const int kt = wave + 4 * ki;
    #pragma unroll
    for (int gg = 0; gg < 4; gg++) {
      #pragma unroll
      for (int p = 0; p < 2; p++)
        wfrag[ki][gg][p] = *(const s8v*)&Wlds[p][gg * 16 + lm][kt * 32 + lq * 8];
    }
  }
  __syncthreads();

  // cell-update thread mapping: one thread per (batch m, h-col)
  const int cm  = tid >> 4;
  const int chc = tid & 15;
  float biasv[4];
  #pragma unroll
  for (int gg = 0; gg < 4; gg++) {
    int col = gg * 256 + ct * 16 + chc;
    biasv[gg] = bih[col] + bhh[col];
  }
  float cstate = 0.0f;

  // x prefetch mapping: thread loads x[g*16+xr][t][xc0..xc0+7]
  const int xr  = tid >> 4;
  const int xc0 = (tid & 15) * 8;
  const float* xbase = x + (size_t)(g * 16 + xr) * (T_ * I_) + xc0;

  u32* gflags = flags + g * 32;                 // 128 B per group
  const size_t hpar   = (size_t)16 * 16 * 256;  // parity stride (u32 elems)
  const size_t hgbase = (size_t)g * 16 * 256;   // group base within parity

  // per-wave peer set for the main-loop spin: wave w consumes h columns of
  // peers {2w, 2w+1, 2w+8, 2w+9} (ki=1 -> first pair, ki=2 -> second pair).
  const int pl   = lane & 3;
  u32* fpeer = gflags + (2 * wave + (pl & 1) + 8 * (pl >> 1));

  auto xstore = [&](int par, float4 a, float4 b) {
    float v[8] = {a.x, a.y, a.z, a.w, b.x, b.y, b.z, b.w};
    union { u16 u[8]; s8v s; } hi, lo;
    #pragma unroll
    for (int j = 0; j < 8; j++) {
      u16 h = f2bf(v[j]);
      hi.u[j] = h;
      lo.u[j] = f2bf(v[j] - bf2f(h));
    }
    *(s8v*)&xlds[par][0][xr][xc0] = hi.s;
    *(s8v*)&xlds[par][1][xr][xc0] = lo.s;
  };

  { // x_0 into parity 0
    float4 a = *(const float4*)(xbase + 0);
    float4 b = *(const float4*)(xbase + 4);
    xstore(0, a, b);
  }
  __syncthreads();

  for (int t = 0; t < T_; t++) {
    const int par = t & 1;
    const int pn  = (t + 1) & 1;

    // prefetch x_{t+1} (clamped; read-only data)
    const int tn = (t + 1 < T_) ? (t + 1) : t;
    float4 xa = *(const float4*)(xbase + (size_t)tn * I_);
    float4 xb = *(const float4*)(xbase + (size_t)tn * I_ + 4);

    f4v acc[4];
    #pragma unroll
    for (int gg = 0; gg < 4; gg++)
      #pragma unroll
      for (int r = 0; r < 4; r++) acc[gg][r] = 0.0f;

    // x-part MFMA (k-tile = wave), independent of peers -> runs before spin.
    {
      s8v axh = *(const s8v*)&xlds[par][0][lm][wave * 32 + lq * 8];
      s8v axl = *(const s8v*)&xlds[par][1][lm][wave * 32 + lq * 8];
      #pragma unroll
      for (int gg = 0; gg < 4; gg++) {
        acc[gg] = __builtin_amdgcn_mfma_f32_16x16x32_bf16(axh, wfrag[0][gg][0], acc[gg], 0, 0, 0);
        acc[gg] = __builtin_amdgcn_mfma_f32_16x16x32_bf16(axl, wfrag[0][gg][0], acc[gg], 0, 0, 0);
        acc[gg] = __builtin_amdgcn_mfma_f32_16x16x32_bf16(axh, wfrag[0][gg][1], acc[gg], 0, 0, 0);
      }
    }

    if (t > 0) {
      // spin until this wave's 4 peers posted h_t (flag==t; skew <=1 -> t+1).
      // 0xAAAAAAAA poison never satisfies (f - t) <= 1. Relaxed agent loads
      // read the coherence point (no buffer_inv).
      const u32 s = (u32)t;
      while (true) {
        u32 f = __hip_atomic_load(fpeer, __ATOMIC_RELAXED, __HIP_MEMORY_SCOPE_AGENT);
        if (__all((int)((f - s) <= 1u))) break;
        __builtin_amdgcn_s_sleep(1);
      }
      asm volatile("" ::: "memory");   // keep h loads below the spin

      const u32* hb0 = hbuf + (size_t)par * hpar + hgbase;
      #pragma unroll
      for (int ki = 1; ki < 3; ki++) {
        const int hk = wave * 32 + (ki - 1) * 128 + lq * 8;   // k within h
        const u64* hp = (const u64*)(hb0 + (size_t)lm * 256 + hk);
        u64 w[4];
        #pragma unroll
        for (int j = 0; j < 4; j++)
          w[j] = __hip_atomic_load(hp + j, __ATOMIC_RELAXED, __HIP_MEMORY_SCOPE_AGENT);
        s8v ahh, ahl;
        unpack8(w, ahh, ahl);
        #pragma unroll
        for (int gg = 0; gg < 4; gg++) {
          acc[gg] = __builtin_amdgcn_mfma_f32_16x16x32_bf16(ahh, wfrag[ki][gg][0], acc[gg], 0, 0, 0);
          acc[gg] = __builtin_amdgcn_mfma_f32_16x16x32_bf16(ahl, wfrag[ki][gg][0], acc[gg], 0, 0, 0);
          acc[gg] = __builtin_amdgcn_mfma_f32_16x16x32_bf16(ahh, wfrag[ki][gg][1], acc[gg], 0, 0, 0);
        }
      }
    }

    // write per-wave partial gates (C layout: col=lm, row=lq*4+r)
    #pragma unroll
    for (int gg = 0; gg < 4; gg++)
      #pragma unroll
      for (int r = 0; r < 4; r++)
        partial[wave][gg][lq * 4 + r][lm] = acc[gg][r];
    __syncthreads();

    // cell update: thread (cm, chc)
    float ga = biasv[0], gb = biasv[1], gc = biasv[2], gd = biasv[3];
    #pragma unroll
    for (int w = 0; w < 4; w++) {
      ga += partial[w][0][cm][chc];
      gb += partial[w][1][cm][chc];
      gc += partial[w][2][cm][chc];
      gd += partial[w][3][cm][chc];
    }
    float i_t = sig_(ga), f_t = sig_(gb), g_t = tanh_(gc), o_t = sig_(gd);
    cstate = f_t * cstate + i_t * g_t;
    float h = o_t * tanh_(cstate);

    // publish h_{t+1}: packed (lo<<16)|hi, coherent write-through store.
    u16 hhi = f2bf(h);
    u16 hlo = f2bf(h - bf2f(hhi));
    u32 pk  = ((u32)hlo << 16) | (u32)hhi;
    u32* hw = hbuf + (size_t)pn * hpar + hgbase + (size_t)cm * 256 + ct * 16 + chc;
    __hip_atomic_store(hw, pk, __ATOMIC_RELAXED, __HIP_MEMORY_SCOPE_AGENT);

    // __syncthreads emits s_waitcnt vmcnt(0) before s_barrier -> all h stores
    // of all 4 waves are at the coherence point before tid0 posts the flag.
    __syncthreads();
    if (tid == 0)
      __hip_atomic_store(gflags + ct, (u32)(t + 1), __ATOMIC_RELAXED, __HIP_MEMORY_SCOPE_AGENT);

    // convert x_{t+1} into the other parity's LDS planes
    xstore(pn, xa, xb);
    __syncthreads();
  }

  // ---- output projection: out = h_T @ W_out + b_out ----
  {
    const u32 s = (u32)T_;
    u32* fp = gflags + lm;   // all 16 peers must have posted h_T
    while (true) {
      u32 f = __hip_atomic_load(fp, __ATOMIC_RELAXED, __HIP_MEMORY_SCOPE_AGENT);
      if (__all((int)((f - s) <= 1u))) break;
      __builtin_amdgcn_s_sleep(1);
    }
    asm volatile("" ::: "memory");
  }
  __syncthreads();
  // stage W_out cols [ct*8, ct*8+8) into Wlds[p][n][k], zero-pad n in [8,16)
  for (int it = tid; it < 16 * 256; it += 256) {
    int n = it >> 8;
    int k = it & 255;
    float w = (n < 8) ? Wout[k * 128 + ct * 8 + n] : 0.0f;
    u16 hi = f2bf(w);
    Wlds[0][n][k] = hi;
    Wlds[1][n][k] = f2bf(w - bf2f(hi));
  }
  __syncthreads();

  f4v oacc;
  #pragma unroll
  for (int r = 0; r < 4; r++) oacc[r] = 0.0f;
  const u32* hb0 = hbuf + hgbase;   // h_T lives at parity (1024 & 1) == 0
  #pragma unroll
  for (int ki = 0; ki < 2; ki++) {
    const int hk = (wave * 2 + ki) * 32 + lq * 8;
    const u64* hp = (const u64*)(hb0 + (size_t)lm * 256 + hk);
    u64 w[4];
    #pragma unroll
    for (int j = 0; j < 4; j++)
      w[j] = __hip_atomic_load(hp + j, __ATOMIC_RELAXED, __HIP_MEMORY_SCOPE_AGENT);
    s8v ahh, ahl;
    unpack8(w, ahh, ahl);
    s8v bh  = *(const s8v*)&Wlds[0][lm][hk];
    s8v bl  = *(const s8v*)&Wlds[1][lm][hk];
    oacc = __builtin_amdgcn_mfma_f32_16x16x32_bf16(ahh, bh, oacc, 0, 0, 0);
    oacc = __builtin_amdgcn_mfma_f32_16x16x32_bf16(ahl, bh, oacc, 0, 0, 0);
    oacc = __builtin_amdgcn_mfma_f32_16x16x32_bf16(ahh, bl, oacc, 0, 0, 0);
  }
  #pragma unroll
  for (int r = 0; r < 4; r++) partial[wave][0][lq * 4 + r][lm] = oacc[r];
  __syncthreads();

  if (tid < 128) {
    int m  = tid >> 3;
    int oc = tid & 7;
    float v = bout[ct * 8 + oc];
    #pragma unroll
    for (int w = 0; w < 4; w++) v += partial[w][0][m][oc];
    out[(size_t)(g * 16 + m) * 128 + ct * 8 + oc] = v;
  }
}

extern "C" void kernel_launch(void* const* d_in, const int* in_sizes, int n_in,
                              void* d_out, int out_size, void* d_ws, size_t ws_size,
                              hipStream_t stream) {
  const float* x    = (const float*)d_in[0];
  const float* Wih  = (const float*)d_in[1];
  const float* Whh  = (const float*)d_in[2];
  const float* bih  = (const float*)d_in[3];
  const float* bhh  = (const float*)d_in[4];
  const float* Wout = (const float*)d_in[5];
  const float* bout = (const float*)d_in[6];
  float* out = (float*)d_out;

  char* ws = (char*)d_ws;
  u32* flags = (u32*)ws;               // 16 groups * 128 B = 2 KB (poison-safe protocol)
  u32* hbuf  = (u32*)(ws + 4096);      // 2 parities * 16 g * 16 * 256 * 4 B = 512 KB

  hipLaunchKernelGGL(lstm_persist, dim3(256), dim3(256), 0, stream,
                     x, Wih, Whh, bih, bhh, Wout, bout, out, flags, hbuf);
}